// Round 1
// baseline (779.005 us; speedup 1.0000x reference)
//
#include <hip/hip_runtime.h>
#include <math.h>

#define B_ 2
#define H_ 12
#define S_ 1024
#define D_ 128
#define KQ_ 6
#define KK_ 11
#define TQ 32
#define TK 32
#define RQ (TQ + KQ_ - 1)     /* 37 score rows (q halo of 5 below) */
#define CK (TK + KK_ - 1)     /* 42 score cols (k halo of +-5)     */
#define NT 256
#define DP (D_ + 4)           /* padded LDS row stride (bank shift) */
#define SCALE 0.08838834764831843f

__global__ __launch_bounds__(NT) void conv_attn_kernel(
    const float* __restrict__ Q, const float* __restrict__ K,
    const float* __restrict__ V, const float* __restrict__ W,
    float* __restrict__ O)
{
    __shared__ float Qs[RQ][DP];        // 37*132*4 = 19536 B
    __shared__ float Ks[CK][DP];        // 42*132*4 = 22176 B
    __shared__ float Sc[RQ][CK + 1];    // 37*43*4  =  6364 B
    __shared__ float Lg[TQ][TK + 1];    // 32*33*4  =  4224 B
    __shared__ float Wf[KQ_ * KK_];
    __shared__ float m_s[TQ], l_s[TQ], a_s[TQ];

    const int tid = threadIdx.x;
    const int bid = blockIdx.x;
    const int bh  = bid % (B_ * H_);          // balance: consecutive bids share qt range spread
    const int qt  = bid / (B_ * H_);
    const int h   = bh % H_;
    const int q0  = qt * TQ;

    const float* Qb = Q + (size_t)bh * S_ * D_;
    const float* Kb = K + (size_t)bh * S_ * D_;
    const float* Vb = V + (size_t)bh * S_ * D_;
    float*       Ob = O + (size_t)bh * S_ * D_;

    if (tid < KQ_ * KK_) Wf[tid] = W[h * KQ_ * KK_ + tid];
    if (tid < TQ) { m_s[tid] = -INFINITY; l_s[tid] = 0.f; a_s[tid] = 0.f; }

    // stage Q rows [q0-5, q0+TQ); out-of-range rows -> 0 (zero-padding)
    for (int idx = tid; idx < RQ * D_; idx += NT) {
        int rr = idx / D_, d = idx - rr * D_;
        int qg = q0 - (KQ_ - 1) + rr;
        Qs[rr][d] = (qg >= 0) ? Qb[(size_t)qg * D_ + d] : 0.f;
    }

    float acc[16];
    #pragma unroll
    for (int e = 0; e < 16; ++e) acc[e] = 0.f;

    const int row = tid & 31;     // output row this thread accumulates
    const int cb  = tid >> 5;     // column block 0..7
    const int c0  = cb * 16;      // first of 16 output cols

    const int nk = q0 + TQ;       // causal: keys beyond q0+TQ-1 are all masked
    for (int k0 = 0; k0 < nk; k0 += TK) {
        __syncthreads();          // prev iteration's reads of Ks/Lg done
        // stage K rows [k0-5, k0+TK+5)
        for (int idx = tid; idx < CK * D_; idx += NT) {
            int rr = idx / D_, d = idx - rr * D_;
            int kg = k0 - (KK_ - 1) / 2 + rr;
            Ks[rr][d] = (kg >= 0 && kg < S_) ? Kb[(size_t)kg * D_ + d] : 0.f;
        }
        __syncthreads();

        // masked score tile: 37 x 42. 222 threads: rr = t/6, 7 cols each.
        if (tid < 222) {
            int rr = tid / 6, cg = tid - rr * 6;
            int ccb = cg * 7;
            int qg = q0 - (KQ_ - 1) + rr;
            float a[7];
            #pragma unroll
            for (int j = 0; j < 7; ++j) a[j] = 0.f;
            const float4* q4 = (const float4*)Qs[rr];
            #pragma unroll 4
            for (int d4 = 0; d4 < D_ / 4; ++d4) {
                float4 qv = q4[d4];
                #pragma unroll
                for (int j = 0; j < 7; ++j) {
                    float4 kv = ((const float4*)Ks[ccb + j])[d4];
                    a[j] += qv.x * kv.x + qv.y * kv.y + qv.z * kv.z + qv.w * kv.w;
                }
            }
            #pragma unroll
            for (int j = 0; j < 7; ++j) {
                int kg = k0 - (KK_ - 1) / 2 + ccb + j;
                bool valid = (qg >= 0) && (kg >= 0) && (kg < S_) && (kg <= qg);
                Sc[rr][ccb + j] = valid ? a[j] : 0.f;
            }
        }
        __syncthreads();

        // 6x11 conv -> logits (scale + causal -inf)
        {
            int r  = tid >> 3;            // 0..31
            int cc = (tid & 7) * 4;       // 0,4,...,28
            int q  = q0 + r;
            #pragma unroll
            for (int cj = 0; cj < 4; ++cj) {
                int c = cc + cj;
                int k = k0 + c;
                float s = 0.f;
                #pragma unroll
                for (int i = 0; i < KQ_; ++i) {
                    #pragma unroll
                    for (int j = 0; j < KK_; ++j)
                        s += Wf[i * KK_ + j] * Sc[r + i][c + j];
                }
                Lg[r][c] = (k <= q) ? s * SCALE : -INFINITY;
            }
        }
        __syncthreads();

        // online softmax row update (one thread per row)
        if (tid < TQ) {
            int r = tid;
            float mx = m_s[r];
            float tmax = -INFINITY;
            #pragma unroll
            for (int c = 0; c < TK; ++c) tmax = fmaxf(tmax, Lg[r][c]);
            float nm = fmaxf(mx, tmax);
            float al = __expf(mx - nm);            // exp(-inf)=0 on first tile
            float sum = 0.f;
            #pragma unroll
            for (int c = 0; c < TK; ++c) {
                float p = __expf(Lg[r][c] - nm);
                Lg[r][c] = p;
                sum += p;
            }
            m_s[r] = nm;
            l_s[r] = l_s[r] * al + sum;
            a_s[r] = al;
        }
        __syncthreads();

        // rescale accumulator + P @ V (V straight from global: broadcast reads, L1-hot)
        {
            float al = a_s[row];
            #pragma unroll
            for (int e = 0; e < 16; ++e) acc[e] *= al;
            #pragma unroll 4
            for (int ck = 0; ck < TK; ++ck) {
                float p = Lg[row][ck];
                const float4* vr = (const float4*)(Vb + (size_t)(k0 + ck) * D_ + c0);
                #pragma unroll
                for (int e4 = 0; e4 < 4; ++e4) {
                    float4 v = vr[e4];
                    acc[e4 * 4 + 0] += p * v.x;
                    acc[e4 * 4 + 1] += p * v.y;
                    acc[e4 * 4 + 2] += p * v.z;
                    acc[e4 * 4 + 3] += p * v.w;
                }
            }
        }
    }

    // epilogue: normalize and store
    {
        float inv = 1.f / l_s[row];
        float4* out4 = (float4*)(Ob + (size_t)(q0 + row) * D_ + c0);
        #pragma unroll
        for (int e4 = 0; e4 < 4; ++e4) {
            float4 o;
            o.x = acc[e4 * 4 + 0] * inv;
            o.y = acc[e4 * 4 + 1] * inv;
            o.z = acc[e4 * 4 + 2] * inv;
            o.w = acc[e4 * 4 + 3] * inv;
            out4[e4] = o;
        }
    }
}

extern "C" void kernel_launch(void* const* d_in, const int* in_sizes, int n_in,
                              void* d_out, int out_size, void* d_ws, size_t ws_size,
                              hipStream_t stream) {
    const float* Q = (const float*)d_in[0];
    const float* K = (const float*)d_in[1];
    const float* V = (const float*)d_in[2];
    const float* W = (const float*)d_in[3];
    float* O = (float*)d_out;
    dim3 grid(B_ * H_ * (S_ / TQ));
    conv_attn_kernel<<<grid, dim3(NT), 0, stream>>>(Q, K, V, W, O);
}

// Round 2
// 200.789 us; speedup vs baseline: 3.8797x; 3.8797x over previous
//
#include <hip/hip_runtime.h>
#include <hip/hip_bf16.h>
#include <math.h>

#define B_ 2
#define H_ 12
#define S_ 1024
#define D_ 128
#define TQ 32
#define TK 32
#define NW 4
#define SCALE 0.08838834764831843f

#define QPAD 16
#define QROWS (S_ + QPAD)          /* 1040 */
#define KPAD 16
#define KROWS (KPAD + S_ + 16)     /* 1056 */

typedef __attribute__((ext_vector_type(8))) short short8;
typedef __attribute__((ext_vector_type(4))) float floatx4;

__device__ __forceinline__ float b2f(short s) {
    unsigned int x = ((unsigned int)(unsigned short)s) << 16;
    return __builtin_bit_cast(float, x);
}
__device__ __forceinline__ unsigned short f2b(float f) {
    return __builtin_bit_cast(unsigned short, __float2bfloat16(f));
}

// ---- prepass: f32 -> bf16 with zero row padding -----------------------------
__global__ __launch_bounds__(256) void cvt_pad_kernel(
    const float* __restrict__ src, unsigned short* __restrict__ dst,
    int rows_total)   // dst[bh][r][d]: r<16 or r-16>=S_ -> 0
{
    int idx = blockIdx.x * 256 + threadIdx.x;
    size_t e0 = (size_t)idx * 4;
    int bh = (int)(e0 / ((size_t)rows_total * D_));
    int rem = (int)(e0 - (size_t)bh * rows_total * D_);
    int r = rem / D_;
    int d = rem - r * D_;
    int sr = r - 16;
    float4 v = make_float4(0.f, 0.f, 0.f, 0.f);
    if (sr >= 0 && sr < S_)
        v = *(const float4*)(src + ((size_t)bh * S_ + sr) * D_ + d);
    ushort4 o;
    o.x = f2b(v.x); o.y = f2b(v.y); o.z = f2b(v.z); o.w = f2b(v.w);
    *(ushort4*)(dst + ((size_t)bh * rows_total + r) * D_ + d) = o;
}

// ---- prepass: V -> V^T bf16  (Vt[bh][d][k]) --------------------------------
__global__ __launch_bounds__(256) void vt_kernel(
    const float* __restrict__ V, unsigned short* __restrict__ Vt)
{
    __shared__ float ls[32][33];
    int b = blockIdx.x;
    int dt = b & 3; int kt = (b >> 2) & 31; int bh = b >> 7;
    int t = threadIdx.x;
    int lk = t >> 3, ld = (t & 7) * 4;
    float4 v = *(const float4*)(V + ((size_t)bh * S_ + kt * 32 + lk) * D_ + dt * 32 + ld);
    ls[lk][ld + 0] = v.x; ls[lk][ld + 1] = v.y; ls[lk][ld + 2] = v.z; ls[lk][ld + 3] = v.w;
    __syncthreads();
    int lk2 = t >> 3, lc = (t & 7) * 4;
    ushort4 o;
    o.x = f2b(ls[lc + 0][lk2]); o.y = f2b(ls[lc + 1][lk2]);
    o.z = f2b(ls[lc + 2][lk2]); o.w = f2b(ls[lc + 3][lk2]);
    *(ushort4*)(Vt + ((size_t)bh * D_ + dt * 32 + lk2) * S_ + kt * 32 + lc) = o;
}

// ---- main fused kernel ------------------------------------------------------
__global__ __launch_bounds__(256, 2) void conv_attn_mfma(
    const unsigned short* __restrict__ Qp,  // [24][1040][128] bf16
    const unsigned short* __restrict__ Kp,  // [24][1056][128] bf16
    const unsigned short* __restrict__ Vt,  // [24][128][1024] bf16
    const float* __restrict__ W,            // [12][6][11]
    float* __restrict__ O)                  // [24][1024][128] f32
{
    __shared__ __align__(16) union {
        unsigned short sc[NW][48][72];      // 27648 B, per-wave score tiles (bf16)
        float oacc[32][132];                // 16896 B, reused for merge
    } u;
    __shared__ float m_all[NW][32], l_all[NW][32], ms_s[32], inv_s[32];

    const int tid = threadIdx.x;
    const int wv = tid >> 6;
    const int ln = tid & 63;
    const int l15 = ln & 15;
    const int qd = ln >> 4;

    const int bid = blockIdx.x;
    const int bh = bid % (B_ * H_);
    const int qt = (S_ / TQ - 1) - bid / (B_ * H_);   // heavy tiles first
    const int h = bh % H_;
    const int q0 = qt * TQ;

    const unsigned short* Qb = Qp + (size_t)bh * QROWS * D_;
    const unsigned short* Kb = Kp + (size_t)bh * KROWS * D_;
    const unsigned short* Vb = Vt + (size_t)bh * D_ * S_;
    const float* Wh = W + h * 66;

    // Q A-fragments, register-resident for the whole block
    short8 qf[3][4];
    #pragma unroll
    for (int mt = 0; mt < 3; ++mt) {
        const unsigned short* row = Qb + (size_t)(q0 + mt * 16 + l15) * D_;
        #pragma unroll
        for (int kc = 0; kc < 4; ++kc)
            qf[mt][kc] = *(const short8*)(row + kc * 32 + qd * 8);
    }

    floatx4 acc[2][8];
    #pragma unroll
    for (int mt = 0; mt < 2; ++mt)
        #pragma unroll
        for (int nt = 0; nt < 8; ++nt)
            acc[mt][nt] = (floatx4){0.f, 0.f, 0.f, 0.f};
    float m_run[2] = {-INFINITY, -INFINITY};
    float l_run[2] = {0.f, 0.f};

    const int nkt = qt + 1;
    for (int kt = wv; kt < nkt; kt += NW) {
        const int k0 = kt * TK;

        // V fragments (independent; issue early, latency hidden by scores+conv)
        short8 vf[8];
        #pragma unroll
        for (int nt = 0; nt < 8; ++nt)
            vf[nt] = *(const short8*)(Vb + (size_t)(nt * 16 + l15) * S_ + k0 + qd * 8);

        // ---- scores: 48x48 tile via MFMA, masked, bf16 -> LDS --------------
        #pragma unroll
        for (int nt = 0; nt < 3; ++nt) {
            const unsigned short* krow = Kb + (size_t)(k0 + 8 + nt * 16 + l15) * D_;
            short8 kf[4];
            #pragma unroll
            for (int kc = 0; kc < 4; ++kc)
                kf[kc] = *(const short8*)(krow + kc * 32 + qd * 8);
            #pragma unroll
            for (int mt = 0; mt < 3; ++mt) {
                floatx4 s = {0.f, 0.f, 0.f, 0.f};
                #pragma unroll
                for (int kc = 0; kc < 4; ++kc)
                    s = __builtin_amdgcn_mfma_f32_16x16x32_bf16(qf[mt][kc], kf[kc], s, 0, 0, 0);
                const int qrow = q0 - 16 + mt * 16 + qd * 4;
                const int kcol = k0 - 8 + nt * 16 + l15;
                #pragma unroll
                for (int reg = 0; reg < 4; ++reg) {
                    float v = (kcol <= qrow + reg) ? s[reg] : 0.f;
                    u.sc[wv][mt * 16 + qd * 4 + reg][nt * 16 + l15] = f2b(v);
                }
            }
        }

        // ---- 6x11 conv on VALU, scores from LDS ----------------------------
        float pl[2][8];
        #pragma unroll
        for (int mt2 = 0; mt2 < 2; ++mt2)
            #pragma unroll
            for (int jj = 0; jj < 8; ++jj) pl[mt2][jj] = 0.f;
        #pragma unroll
        for (int i = 0; i < 6; ++i) {
            const unsigned short* r0 = &u.sc[wv][l15 + 11 + i][qd * 8];
            const unsigned short* r1 = &u.sc[wv][l15 + 27 + i][qd * 8];
            short8 h0 = *(const short8*)(r0);
            short8 h1 = *(const short8*)(r0 + 8);
            short8 h2 = *(const short8*)(r0 + 16);
            short8 g0 = *(const short8*)(r1);
            short8 g1 = *(const short8*)(r1 + 8);
            short8 g2 = *(const short8*)(r1 + 16);
            float x0[24], x1[24];
            #pragma unroll
            for (int m = 0; m < 8; ++m) {
                x0[m] = b2f(h0[m]); x0[8 + m] = b2f(h1[m]); x0[16 + m] = b2f(h2[m]);
                x1[m] = b2f(g0[m]); x1[8 + m] = b2f(g1[m]); x1[16 + m] = b2f(g2[m]);
            }
            #pragma unroll
            for (int j = 0; j < 11; ++j) {
                const float w = Wh[i * 11 + j];   // uniform -> s_load, SGPR
                #pragma unroll
                for (int jj = 0; jj < 8; ++jj) {
                    pl[0][jj] += w * x0[3 + j + jj];
                    pl[1][jj] += w * x1[3 + j + jj];
                }
            }
        }

        // ---- online softmax (per wave, rows split across quads) ------------
        float al[2];
        short8 pfrag[2];
        #pragma unroll
        for (int mt2 = 0; mt2 < 2; ++mt2) {
            const int qrow = q0 + l15 + 16 * mt2;
            float lg[8];
            float mx = -1e30f;
            #pragma unroll
            for (int jj = 0; jj < 8; ++jj) {
                const int kcol = k0 + qd * 8 + jj;
                lg[jj] = (kcol <= qrow) ? pl[mt2][jj] * SCALE : -1e30f;
                mx = fmaxf(mx, lg[jj]);
            }
            mx = fmaxf(mx, __shfl_xor(mx, 16));
            mx = fmaxf(mx, __shfl_xor(mx, 32));
            const float nm = fmaxf(m_run[mt2], mx);
            al[mt2] = __expf(m_run[mt2] - nm);
            float sum = 0.f;
            short8 pb;
            #pragma unroll
            for (int jj = 0; jj < 8; ++jj) {
                float p = __expf(lg[jj] - nm);
                sum += p;
                pb[jj] = (short)f2b(p);
            }
            sum += __shfl_xor(sum, 16);
            sum += __shfl_xor(sum, 32);
            l_run[mt2] = l_run[mt2] * al[mt2] + sum;
            m_run[mt2] = nm;
            pfrag[mt2] = pb;
        }

        // rescale accumulator: alpha for acc row qd*4+reg lives on lane qd*4+reg
        #pragma unroll
        for (int mt = 0; mt < 2; ++mt) {
            #pragma unroll
            for (int reg = 0; reg < 4; ++reg) {
                const float af = __shfl(al[mt], qd * 4 + reg, 64);
                #pragma unroll
                for (int nt = 0; nt < 8; ++nt)
                    acc[mt][nt][reg] *= af;
            }
        }

        // ---- P @ V via MFMA -------------------------------------------------
        #pragma unroll
        for (int nt = 0; nt < 8; ++nt)
            #pragma unroll
            for (int mt = 0; mt < 2; ++mt)
                acc[mt][nt] = __builtin_amdgcn_mfma_f32_16x16x32_bf16(pfrag[mt], vf[nt], acc[mt][nt], 0, 0, 0);
    }

    // ---- merge the 4 waves' partials ---------------------------------------
    if (qd == 0) {
        m_all[wv][l15] = m_run[0]; m_all[wv][l15 + 16] = m_run[1];
        l_all[wv][l15] = l_run[0]; l_all[wv][l15 + 16] = l_run[1];
    }
    __syncthreads();
    if (tid < 32) {
        float ms = -INFINITY;
        #pragma unroll
        for (int w = 0; w < NW; ++w) ms = fmaxf(ms, m_all[w][tid]);
        float ls = 0.f;
        #pragma unroll
        for (int w = 0; w < NW; ++w) ls += __expf(m_all[w][tid] - ms) * l_all[w][tid];
        ms_s[tid] = ms;
        inv_s[tid] = 1.f / ls;
    }
    __syncthreads();
    for (int w = 0; w < NW; ++w) {
        if (wv == w) {
            #pragma unroll
            for (int mt = 0; mt < 2; ++mt) {
                #pragma unroll
                for (int reg = 0; reg < 4; ++reg) {
                    const int row = mt * 16 + qd * 4 + reg;
                    const float f = __expf(m_all[wv][row] - ms_s[row]);
                    #pragma unroll
                    for (int nt = 0; nt < 8; ++nt) {
                        const float val = acc[mt][nt][reg] * f;
                        if (w == 0) u.oacc[row][nt * 16 + l15] = val;
                        else        u.oacc[row][nt * 16 + l15] += val;
                    }
                }
            }
        }
        __syncthreads();
    }

    // ---- normalize + store --------------------------------------------------
    {
        const int r = tid >> 3;
        const int c0 = (tid & 7) * 16;
        const float inv = inv_s[r];
        float* orow = O + ((size_t)bh * S_ + q0 + r) * D_ + c0;
        #pragma unroll
        for (int g = 0; g < 4; ++g) {
            float4 o;
            o.x = u.oacc[r][c0 + g * 4 + 0] * inv;
            o.y = u.oacc[r][c0 + g * 4 + 1] * inv;
            o.z = u.oacc[r][c0 + g * 4 + 2] * inv;
            o.w = u.oacc[r][c0 + g * 4 + 3] * inv;
            *(float4*)(orow + g * 4) = o;
        }
    }
}

extern "C" void kernel_launch(void* const* d_in, const int* in_sizes, int n_in,
                              void* d_out, int out_size, void* d_ws, size_t ws_size,
                              hipStream_t stream) {
    const float* Q = (const float*)d_in[0];
    const float* K = (const float*)d_in[1];
    const float* V = (const float*)d_in[2];
    const float* W = (const float*)d_in[3];
    float* O = (float*)d_out;

    // ws layout (needs ~19.2 MB)
    unsigned short* Qp = (unsigned short*)d_ws;                        // 24*1040*128*2 = 6389760
    unsigned short* Kp = (unsigned short*)((char*)d_ws + 6389760);     // 24*1056*128*2 = 6488064
    unsigned short* Vt = (unsigned short*)((char*)d_ws + 12877824);    // 24*128*1024*2 = 6291456

    cvt_pad_kernel<<<dim3((B_ * H_ * QROWS * D_) / 1024), dim3(256), 0, stream>>>(Q, Qp, QROWS);
    cvt_pad_kernel<<<dim3((B_ * H_ * KROWS * D_) / 1024), dim3(256), 0, stream>>>(K, Kp, KROWS);
    vt_kernel<<<dim3(B_ * H_ * (S_ / 32) * (D_ / 32)), dim3(256), 0, stream>>>(V, Vt);

    conv_attn_mfma<<<dim3(B_ * H_ * (S_ / TQ)), dim3(256), 0, stream>>>(Qp, Kp, Vt, W, O);
}